// Round 3
// baseline (312.013 us; speedup 1.0000x reference)
//
#include <hip/hip_runtime.h>
#include <hip/hip_bf16.h>
#include <stdint.h>

#define D_MODEL 1024
#define NHEADS  16
#define HDIM    64
#define BB      2
#define TT      2048
#define MROWS   (BB*TT)      // 4096
#define GK      1024         // reduction dim for all projections

typedef __bf16 bf16_8 __attribute__((ext_vector_type(8)));
typedef float  f32x4  __attribute__((ext_vector_type(4)));
typedef unsigned short u16;

__device__ __forceinline__ u16 f2bf(float f) {
    union { float f; uint32_t u; } c; c.f = f;
    uint32_t u = c.u;
    uint32_t r = (u + 0x7FFFu + ((u >> 16) & 1u)) >> 16;
    return (u16)r;
}
__device__ __forceinline__ uint32_t pk2bf(float a, float b) {
    return (uint32_t)f2bf(a) | ((uint32_t)f2bf(b) << 16);
}

__device__ __forceinline__ void gload16(const void* g, void* l) {
    __builtin_amdgcn_global_load_lds(
        (const __attribute__((address_space(1))) unsigned int*)g,
        (__attribute__((address_space(3))) unsigned int*)l,
        16, 0, 0);
}

// ---------------------------------------------------------------- convert
__global__ __launch_bounds__(256) void cvtk(
    const float* __restrict__ x,  const float* __restrict__ wq,
    const float* __restrict__ wk, const float* __restrict__ wv,
    const float* __restrict__ wo,
    u16* __restrict__ xb,  u16* __restrict__ wqb, u16* __restrict__ wkb,
    u16* __restrict__ wvb, u16* __restrict__ wob)
{
    int z = blockIdx.y;
    const float* in; u16* out; int n4;
    switch (z) {
        case 0: in = x;  out = xb;  n4 = MROWS*D_MODEL/4; break;
        case 1: in = wq; out = wqb; n4 = D_MODEL*D_MODEL/4; break;
        case 2: in = wk; out = wkb; n4 = D_MODEL*D_MODEL/4; break;
        case 3: in = wv; out = wvb; n4 = D_MODEL*D_MODEL/4; break;
        default: in = wo; out = wob; n4 = D_MODEL*D_MODEL/4; break;
    }
    for (int i = blockIdx.x*256 + threadIdx.x; i < n4; i += 1024*256) {
        float4 v = ((const float4*)in)[i];
        uint2 pk;
        pk.x = pk2bf(v.x, v.y);
        pk.y = pk2bf(v.z, v.w);
        ((uint2*)out)[i] = pk;
    }
}

// ---------------------------------------------------------------- GEMM body
// C(128x128) tile of A(4096x1024) * B(1024x1024)^T, both bf16 row-major.
// MODE 0: scatter bf16 into (B,H,T,D)   [Q (scaled), K]
// MODE 1: swapped-operand MFMA; store bf16 into (B,H,D,T) coalesced  [V^T]
// MODE 2: f32 row-major (4096x1024)     [final out]
template<int MODE>
__device__ __forceinline__ void gemm_body(
    const u16* __restrict__ A, const u16* __restrict__ Bm,
    void* __restrict__ dst, float oscale)
{
    __shared__ u16 As[128*64];
    __shared__ u16 Bs[128*64];
    const int tid  = threadIdx.x;
    const int lane = tid & 63, w = tid >> 6;
    const int wr = w >> 1, wc = w & 1;
    const int g = lane >> 4, lr = lane & 15;
    const int bn = blockIdx.x & 7, bm = blockIdx.x >> 3;
    const int m0 = bm * 128, n0 = bn * 128;

    f32x4 acc[4][4];
    #pragma unroll
    for (int i = 0; i < 4; ++i)
        #pragma unroll
        for (int j = 0; j < 4; ++j)
            acc[i][j] = f32x4{0.f, 0.f, 0.f, 0.f};

    for (int k0 = 0; k0 < GK; k0 += 64) {
        #pragma unroll
        for (int r = 0; r < 4; ++r) {
            int o   = r*256 + tid;
            int row = o >> 3;
            int lc  = (o & 7) ^ (row & 7);
            const char* ga = (const char*)(A  + (size_t)(m0+row)*GK + k0 + lc*8);
            const char* gb = (const char*)(Bm + (size_t)(n0+row)*GK + k0 + lc*8);
            char* la = (char*)As + (size_t)(r*256 + w*64)*16;
            char* lb = (char*)Bs + (size_t)(r*256 + w*64)*16;
            gload16(ga, la);
            gload16(gb, lb);
        }
        __syncthreads();
        #pragma unroll
        for (int ks = 0; ks < 2; ++ks) {
            bf16_8 af[4], bfr[4];
            #pragma unroll
            for (int mt = 0; mt < 4; ++mt) {
                int row = wr*64 + mt*16 + lr;
                int ch  = (ks*4 + g) ^ (row & 7);
                af[mt] = *(const bf16_8*)((const char*)As + row*128 + ch*16);
            }
            #pragma unroll
            for (int nt = 0; nt < 4; ++nt) {
                int row = wc*64 + nt*16 + lr;
                int ch  = (ks*4 + g) ^ (row & 7);
                bfr[nt] = *(const bf16_8*)((const char*)Bs + row*128 + ch*16);
            }
            #pragma unroll
            for (int mt = 0; mt < 4; ++mt)
                #pragma unroll
                for (int nt = 0; nt < 4; ++nt) {
                    if (MODE == 1)
                        acc[mt][nt] = __builtin_amdgcn_mfma_f32_16x16x32_bf16(
                            bfr[nt], af[mt], acc[mt][nt], 0, 0, 0);
                    else
                        acc[mt][nt] = __builtin_amdgcn_mfma_f32_16x16x32_bf16(
                            af[mt], bfr[nt], acc[mt][nt], 0, 0, 0);
                }
        }
        __syncthreads();
    }

    #pragma unroll
    for (int mt = 0; mt < 4; ++mt) {
        #pragma unroll
        for (int nt = 0; nt < 4; ++nt) {
            #pragma unroll
            for (int r = 0; r < 4; ++r) {
                float v = acc[mt][nt][r];
                if (MODE == 2) {
                    int row = m0 + wr*64 + mt*16 + g*4 + r;
                    int col = n0 + wc*64 + nt*16 + lr;
                    ((float*)dst)[(size_t)row*D_MODEL + col] = v;
                } else if (MODE == 0) {
                    int row = m0 + wr*64 + mt*16 + g*4 + r;   // m: (b,t)
                    int col = n0 + wc*64 + nt*16 + lr;        // n: (h,d)
                    int b = row >> 11, t = row & (TT-1);
                    int h = col >> 6,  d = col & 63;
                    ((u16*)dst)[(((size_t)(b*NHEADS + h)*TT + t)*HDIM + d)] = f2bf(v*oscale);
                } else {  // MODE 1: acc row = n-side (h,d), col = m-side (b,t)
                    int nrow = n0 + wc*64 + nt*16 + g*4 + r;  // n: (h,d)
                    int mcol = m0 + wr*64 + mt*16 + lr;       // m: (b,t)
                    int h = nrow >> 6,  d = nrow & 63;
                    int b = mcol >> 11, t = mcol & (TT-1);
                    ((u16*)dst)[(((size_t)(b*NHEADS + h)*HDIM + d)*TT + t)] = f2bf(v);
                }
            }
        }
    }
}

__global__ __launch_bounds__(256) void gemm_qkv(
    const u16* __restrict__ xb,
    const u16* __restrict__ wqb, const u16* __restrict__ wkb, const u16* __restrict__ wvb,
    u16* __restrict__ Qb, u16* __restrict__ Kb, u16* __restrict__ VTb)
{
    int z = blockIdx.y;
    if (z == 0)      gemm_body<0>(xb, wqb, Qb, 0.18033688f);  // 1/8 * log2(e)
    else if (z == 1) gemm_body<0>(xb, wkb, Kb, 1.0f);
    else             gemm_body<1>(xb, wvb, VTb, 1.0f);
}

__global__ __launch_bounds__(256) void gemm_out(
    const u16* __restrict__ AOb, const u16* __restrict__ wob, float* __restrict__ out)
{
    gemm_body<2>(AOb, wob, out, 1.0f);
}

// ---------------------------------------------------------------- attention
// grid (T/64, B*H); 4 independent waves/block (NO barriers); wave owns 16 q
// rows (q = lane&15, swapped layout); KVBLK=64 loaded global->VGPR per wave.
// O kept transposed (O^T[d][q], col=q=lane&15) so softmax rescale is per-lane.
__global__ __launch_bounds__(256, 4) void attn_fwd(
    const u16* __restrict__ Qb, const u16* __restrict__ Kb,
    const u16* __restrict__ VTb, const unsigned char* __restrict__ mask,
    u16* __restrict__ AO)
{
    __shared__ u16 Pl[4][1152];           // per-wave scratch: P tile / O^T transpose

    const int tid = threadIdx.x, lane = tid & 63, w = tid >> 6;
    const int g = lane >> 4, lr = lane & 15;
    const int bh = blockIdx.y, b = bh >> 4, h = bh & 15;
    const int qt = gridDim.x - 1 - blockIdx.x;       // heavy tiles first
    const int q0 = qt*64 + w*16;

    const u16* Qh = Qb  + (size_t)bh*TT*HDIM;
    const u16* Kh = Kb  + (size_t)bh*TT*HDIM;
    const u16* Vh = VTb + (size_t)bh*HDIM*TT;
    const unsigned char* mk = mask + b*TT;
    char* Pw = (char*)&Pl[w][0];

    // Q B-frags: lane holds Q[q0+lr][dc*32 + g*8 + j]  (pre-scaled by log2e/8)
    bf16_8 qf[2];
    #pragma unroll
    for (int dc = 0; dc < 2; ++dc)
        qf[dc] = *(const bf16_8*)(Qh + (size_t)(q0+lr)*HDIM + dc*32 + g*8);

    f32x4 o[4];                            // O^T: o[dt][r] = O[dt*16+4g+r][q=lr]
    #pragma unroll
    for (int i = 0; i < 4; ++i) o[i] = f32x4{0.f, 0.f, 0.f, 0.f};
    float m_run = -1e30f, l_run = 0.f;

    const int q = q0 + lr;
    const int nt = (q0 + 15)/64 + 1;

    for (int t = 0; t < nt; ++t) {
        const int kv0 = t*64;

        // ---- K A-frags: lane holds K[kv0+kvb*16+lr][dc*32+g*8+j]
        bf16_8 kf[4][2];
        #pragma unroll
        for (int kvb = 0; kvb < 4; ++kvb)
            #pragma unroll
            for (int dc = 0; dc < 2; ++dc)
                kf[kvb][dc] = *(const bf16_8*)(Kh + (size_t)(kv0+kvb*16+lr)*HDIM + dc*32 + g*8);

        // ---- QK^T swapped: s[kvb] lane: q=q0+lr, kv=kv0+kvb*16+4g+reg
        f32x4 s[4];
        #pragma unroll
        for (int kvb = 0; kvb < 4; ++kvb) {
            f32x4 z = f32x4{0.f, 0.f, 0.f, 0.f};
            z = __builtin_amdgcn_mfma_f32_16x16x32_bf16(kf[kvb][0], qf[0], z, 0, 0, 0);
            z = __builtin_amdgcn_mfma_f32_16x16x32_bf16(kf[kvb][1], qf[1], z, 0, 0, 0);
            s[kvb] = z;
        }

        // ---- V^T A-frags for PV (issued early; consumed after softmax)
        bf16_8 vf[4][2];
        #pragma unroll
        for (int dt = 0; dt < 4; ++dt)
            #pragma unroll
            for (int hh = 0; hh < 2; ++hh)
                vf[dt][hh] = *(const bf16_8*)(Vh + (size_t)(dt*16+lr)*TT + kv0 + hh*32 + g*8);

        // ---- mask: padding always; causal only on diagonal (last) tile
        const bool last = (t == nt-1);
        #pragma unroll
        for (int kvb = 0; kvb < 4; ++kvb) {
            uchar4 pm = *(const uchar4*)(mk + kv0 + kvb*16 + 4*g);
            int kvbase = kv0 + kvb*16 + 4*g;
            unsigned char pmr[4] = {pm.x, pm.y, pm.z, pm.w};
            #pragma unroll
            for (int r = 0; r < 4; ++r) {
                bool dead = pmr[r] || (last && (kvbase + r > q));
                if (dead) s[kvb][r] = -1e30f;
            }
        }

        // ---- online softmax in exp2 domain (stats per-lane at q=lr)
        float t0 = fmaxf(fmaxf(s[0][0], s[0][1]), fmaxf(s[0][2], s[0][3]));
        float t1 = fmaxf(fmaxf(s[1][0], s[1][1]), fmaxf(s[1][2], s[1][3]));
        float t2 = fmaxf(fmaxf(s[2][0], s[2][1]), fmaxf(s[2][2], s[2][3]));
        float t3 = fmaxf(fmaxf(s[3][0], s[3][1]), fmaxf(s[3][2], s[3][3]));
        float mx = fmaxf(fmaxf(t0, t1), fmaxf(t2, t3));
        mx = fmaxf(mx, __shfl_xor(mx, 16));
        mx = fmaxf(mx, __shfl_xor(mx, 32));
        float newm = fmaxf(m_run, mx);
        float fsc  = __builtin_amdgcn_exp2f(m_run - newm);
        m_run = newm;

        #pragma unroll
        for (int kvb = 0; kvb < 4; ++kvb)
            #pragma unroll
            for (int r = 0; r < 4; ++r)
                s[kvb][r] = __builtin_amdgcn_exp2f(s[kvb][r] - newm);

        float p0 = (s[0][0] + s[0][1]) + (s[0][2] + s[0][3]);
        float p1 = (s[1][0] + s[1][1]) + (s[1][2] + s[1][3]);
        float p2 = (s[2][0] + s[2][1]) + (s[2][2] + s[2][3]);
        float p3 = (s[3][0] + s[3][1]) + (s[3][2] + s[3][3]);
        float ps = (p0 + p1) + (p2 + p3);
        ps += __shfl_xor(ps, 16);
        ps += __shfl_xor(ps, 32);
        l_run = l_run*fsc + ps;

        // ---- rescale O^T: fsc is per-lane (q=lr) — no shuffles
        #pragma unroll
        for (int dt = 0; dt < 4; ++dt)
            #pragma unroll
            for (int r = 0; r < 4; ++r)
                o[dt][r] *= fsc;

        // ---- P -> LDS (per-wave; C-layout in, B-frag layout out)
        #pragma unroll
        for (int kvb = 0; kvb < 4; ++kvb) {
            *(uint32_t*)(Pw + lr*144 + kvb*32 + g*8 + 0) = pk2bf(s[kvb][0], s[kvb][1]);
            *(uint32_t*)(Pw + lr*144 + kvb*32 + g*8 + 4) = pk2bf(s[kvb][2], s[kvb][3]);
        }
        asm volatile("s_waitcnt lgkmcnt(0)" ::: "memory");
        __builtin_amdgcn_sched_barrier(0);

        // ---- PV swapped: O^T[d][q] += V^T A-frag x P B-frag
        #pragma unroll
        for (int hh = 0; hh < 2; ++hh) {
            bf16_8 pa = *(const bf16_8*)(Pw + lr*144 + hh*64 + g*16);
            #pragma unroll
            for (int dt = 0; dt < 4; ++dt)
                o[dt] = __builtin_amdgcn_mfma_f32_16x16x32_bf16(vf[dt][hh], pa, o[dt], 0, 0, 0);
        }
    }

    // ---- epilogue: divide (per-lane), transpose O^T->O via LDS, store coalesced
    float linv = (l_run > 0.f) ? 1.f/l_run : 0.f;
    u16* ot = (u16*)Pw;                    // [d 64][q 16] stride 17
    #pragma unroll
    for (int dt = 0; dt < 4; ++dt)
        #pragma unroll
        for (int r = 0; r < 4; ++r)
            ot[(dt*16 + 4*g + r)*17 + lr] = f2bf(o[dt][r]*linv);
    asm volatile("s_waitcnt lgkmcnt(0)" ::: "memory");
    __builtin_amdgcn_sched_barrier(0);
    #pragma unroll
    for (int qq = 0; qq < 16; ++qq)
        AO[((size_t)(b*TT + q0 + qq))*D_MODEL + h*HDIM + lane] = ot[lane*17 + qq];
}

// ---------------------------------------------------------------- launch
extern "C" void kernel_launch(void* const* d_in, const int* in_sizes, int n_in,
                              void* d_out, int out_size, void* d_ws, size_t ws_size,
                              hipStream_t stream)
{
    const float* x  = (const float*)d_in[0];
    const unsigned char* mask = (const unsigned char*)d_in[1];
    const float* Wq = (const float*)d_in[2];
    const float* Wk = (const float*)d_in[3];
    const float* Wv = (const float*)d_in[4];
    const float* Wo = (const float*)d_in[5];
    float* out = (float*)d_out;

    char* ws = (char*)d_ws;
    u16* xb  = (u16*)(ws + 0);          // 8 MB (reused as AO after QKV)
    u16* wqb = (u16*)(ws + 8388608);
    u16* wkb = (u16*)(ws + 10485760);
    u16* wvb = (u16*)(ws + 12582912);
    u16* wob = (u16*)(ws + 14680064);
    u16* Qb  = (u16*)(ws + 16777216);
    u16* Kb  = (u16*)(ws + 25165824);
    u16* VTb = (u16*)(ws + 33554432);
    u16* AOb = xb;

    cvtk<<<dim3(1024, 5), 256, 0, stream>>>(x, Wq, Wk, Wv, Wo, xb, wqb, wkb, wvb, wob);
    gemm_qkv<<<dim3(256, 3), 256, 0, stream>>>(xb, wqb, wkb, wvb, Qb, Kb, VTb);
    attn_fwd<<<dim3(TT/64, BB*NHEADS), 256, 0, stream>>>(Qb, Kb, VTb, mask, AOb);
    gemm_out<<<dim3(256), 256, 0, stream>>>(AOb, wob, out);
}

// Round 4
// 147.203 us; speedup vs baseline: 2.1196x; 2.1196x over previous
//
#include <hip/hip_runtime.h>
#include <hip/hip_bf16.h>
#include <stdint.h>

#define D_MODEL 1024
#define NHEADS  16
#define HDIM    64
#define BB      2
#define TT      2048
#define MROWS   (BB*TT)      // 4096
#define GK      1024         // reduction dim for all projections

typedef __bf16 bf16_8 __attribute__((ext_vector_type(8)));
typedef __bf16 bf16_4 __attribute__((ext_vector_type(4)));
typedef float  f32x4  __attribute__((ext_vector_type(4)));
typedef unsigned short u16;

__device__ __forceinline__ u16 f2bf(float f) {
    union { float f; uint32_t u; } c; c.f = f;
    uint32_t u = c.u;
    uint32_t r = (u + 0x7FFFu + ((u >> 16) & 1u)) >> 16;
    return (u16)r;
}
__device__ __forceinline__ uint32_t pk2bf(float a, float b) {
    return (uint32_t)f2bf(a) | ((uint32_t)f2bf(b) << 16);
}

__device__ __forceinline__ void gload16(const void* g, void* l) {
    __builtin_amdgcn_global_load_lds(
        (const __attribute__((address_space(1))) unsigned int*)g,
        (__attribute__((address_space(3))) unsigned int*)l,
        16, 0, 0);
}

// ---------------------------------------------------------------- convert
__global__ __launch_bounds__(256) void cvtk(
    const float* __restrict__ x,  const float* __restrict__ wq,
    const float* __restrict__ wk, const float* __restrict__ wv,
    const float* __restrict__ wo, const unsigned char* __restrict__ mk,
    u16* __restrict__ xb,  u16* __restrict__ wqb, u16* __restrict__ wkb,
    u16* __restrict__ wvb, u16* __restrict__ wob, uint32_t* __restrict__ pmb)
{
    int z = blockIdx.y;
    if (z == 5) {   // pack padding mask into bits: pmb[b*64 + i], bit j = mask[b][32i+j]
        int gi = blockIdx.x*256 + threadIdx.x;
        if (gi < BB*TT/32) {
            uint32_t wv = 0;
            #pragma unroll
            for (int j = 0; j < 32; ++j)
                wv |= (mk[gi*32 + j] ? 1u : 0u) << j;
            pmb[gi] = wv;
        }
        return;
    }
    const float* in; u16* out; int n4;
    switch (z) {
        case 0: in = x;  out = xb;  n4 = MROWS*D_MODEL/4; break;
        case 1: in = wq; out = wqb; n4 = D_MODEL*D_MODEL/4; break;
        case 2: in = wk; out = wkb; n4 = D_MODEL*D_MODEL/4; break;
        case 3: in = wv; out = wvb; n4 = D_MODEL*D_MODEL/4; break;
        default: in = wo; out = wob; n4 = D_MODEL*D_MODEL/4; break;
    }
    for (int i = blockIdx.x*256 + threadIdx.x; i < n4; i += 1024*256) {
        float4 v = ((const float4*)in)[i];
        uint2 pk;
        pk.x = pk2bf(v.x, v.y);
        pk.y = pk2bf(v.z, v.w);
        ((uint2*)out)[i] = pk;
    }
}

// ---------------------------------------------------------------- GEMM body
// C(128x128) tile of A(4096x1024) * B(1024x1024)^T, both bf16 row-major.
// MODE 0: scatter bf16 into (B,H,T,D)   [Q (scaled), K]
// MODE 1: swapped-operand MFMA; store bf16 into (B,H,D,T) coalesced  [V^T]
// MODE 2: f32 row-major (4096x1024)     [final out]
template<int MODE>
__device__ __forceinline__ void gemm_body(
    const u16* __restrict__ A, const u16* __restrict__ Bm,
    void* __restrict__ dst, float oscale)
{
    __shared__ u16 As[128*64];
    __shared__ u16 Bs[128*64];
    const int tid  = threadIdx.x;
    const int lane = tid & 63, w = tid >> 6;
    const int wr = w >> 1, wc = w & 1;
    const int g = lane >> 4, lr = lane & 15;
    const int bn = blockIdx.x & 7, bm = blockIdx.x >> 3;
    const int m0 = bm * 128, n0 = bn * 128;

    f32x4 acc[4][4];
    #pragma unroll
    for (int i = 0; i < 4; ++i)
        #pragma unroll
        for (int j = 0; j < 4; ++j)
            acc[i][j] = f32x4{0.f, 0.f, 0.f, 0.f};

    for (int k0 = 0; k0 < GK; k0 += 64) {
        #pragma unroll
        for (int r = 0; r < 4; ++r) {
            int o   = r*256 + tid;
            int row = o >> 3;
            int lc  = (o & 7) ^ (row & 7);
            const char* ga = (const char*)(A  + (size_t)(m0+row)*GK + k0 + lc*8);
            const char* gb = (const char*)(Bm + (size_t)(n0+row)*GK + k0 + lc*8);
            char* la = (char*)As + (size_t)(r*256 + w*64)*16;
            char* lb = (char*)Bs + (size_t)(r*256 + w*64)*16;
            gload16(ga, la);
            gload16(gb, lb);
        }
        __syncthreads();
        #pragma unroll
        for (int ks = 0; ks < 2; ++ks) {
            bf16_8 af[4], bfr[4];
            #pragma unroll
            for (int mt = 0; mt < 4; ++mt) {
                int row = wr*64 + mt*16 + lr;
                int ch  = (ks*4 + g) ^ (row & 7);
                af[mt] = *(const bf16_8*)((const char*)As + row*128 + ch*16);
            }
            #pragma unroll
            for (int nt = 0; nt < 4; ++nt) {
                int row = wc*64 + nt*16 + lr;
                int ch  = (ks*4 + g) ^ (row & 7);
                bfr[nt] = *(const bf16_8*)((const char*)Bs + row*128 + ch*16);
            }
            #pragma unroll
            for (int mt = 0; mt < 4; ++mt)
                #pragma unroll
                for (int nt = 0; nt < 4; ++nt) {
                    if (MODE == 1)
                        acc[mt][nt] = __builtin_amdgcn_mfma_f32_16x16x32_bf16(
                            bfr[nt], af[mt], acc[mt][nt], 0, 0, 0);
                    else
                        acc[mt][nt] = __builtin_amdgcn_mfma_f32_16x16x32_bf16(
                            af[mt], bfr[nt], acc[mt][nt], 0, 0, 0);
                }
        }
        __syncthreads();
    }

    #pragma unroll
    for (int mt = 0; mt < 4; ++mt) {
        #pragma unroll
        for (int nt = 0; nt < 4; ++nt) {
            #pragma unroll
            for (int r = 0; r < 4; ++r) {
                float v = acc[mt][nt][r];
                if (MODE == 2) {
                    int row = m0 + wr*64 + mt*16 + g*4 + r;
                    int col = n0 + wc*64 + nt*16 + lr;
                    ((float*)dst)[(size_t)row*D_MODEL + col] = v;
                } else if (MODE == 0) {
                    int row = m0 + wr*64 + mt*16 + g*4 + r;   // m: (b,t)
                    int col = n0 + wc*64 + nt*16 + lr;        // n: (h,d)
                    int b = row >> 11, t = row & (TT-1);
                    int h = col >> 6,  d = col & 63;
                    ((u16*)dst)[(((size_t)(b*NHEADS + h)*TT + t)*HDIM + d)] = f2bf(v*oscale);
                } else {  // MODE 1: acc row = n-side (h,d), col = m-side (b,t)
                    int nrow = n0 + wc*64 + nt*16 + g*4 + r;  // n: (h,d)
                    int mcol = m0 + wr*64 + mt*16 + lr;       // m: (b,t)
                    int h = nrow >> 6,  d = nrow & 63;
                    int b = mcol >> 11, t = mcol & (TT-1);
                    ((u16*)dst)[(((size_t)(b*NHEADS + h)*HDIM + d)*TT + t)] = f2bf(v);
                }
            }
        }
    }
}

__global__ __launch_bounds__(256) void gemm_qkv(
    const u16* __restrict__ xb,
    const u16* __restrict__ wqb, const u16* __restrict__ wkb, const u16* __restrict__ wvb,
    u16* __restrict__ Qb, u16* __restrict__ Kb, u16* __restrict__ VTb)
{
    int z = blockIdx.y;
    if (z == 0)      gemm_body<0>(xb, wqb, Qb, 0.18033688f);  // (1/8)*log2(e)
    else if (z == 1) gemm_body<0>(xb, wkb, Kb, 1.0f);
    else             gemm_body<1>(xb, wvb, VTb, 1.0f);
}

__global__ __launch_bounds__(256) void gemm_out(
    const u16* __restrict__ AOb, const u16* __restrict__ wob, float* __restrict__ out)
{
    gemm_body<2>(AOb, wob, out, 1.0f);
}

// ---------------------------------------------------------------- attention
// grid (T/128, B*H); 4 waves x 32 q-rows; KVBLK=64 double-buffered in LDS.
// 2-phase template: STAGE(t+1); compute(t); vmcnt(0); s_barrier  (1 barrier/tile)
__global__ __launch_bounds__(256, 2) void attn_fwd(
    const u16* __restrict__ Qb, const u16* __restrict__ Kb,
    const u16* __restrict__ VTb, const uint32_t* __restrict__ pmb,
    u16* __restrict__ AO)
{
    __shared__ u16 Ks[2][64*64];      // 16 KB  [buf][kv 64][d 64] chunk-XOR-swizzled
    __shared__ u16 Vs[2][64*64];      // 16 KB  [buf][d 64][kv 64]
    __shared__ u16 Pl[4][2304];       // 18 KB  per-wave P / epilogue transpose

    const int tid = threadIdx.x, lane = tid & 63, w = tid >> 6;
    const int g = lane >> 4, lr = lane & 15;
    const int bh = blockIdx.y, b = bh >> 4, h = bh & 15;
    const int qt = gridDim.x - 1 - blockIdx.x;       // heavy tiles first
    const int qlo = qt*128 + w*32;                   // wave's 32 q-rows

    const u16* Qh = Qb  + (size_t)bh*TT*HDIM;
    const u16* Kh = Kb  + (size_t)bh*TT*HDIM;
    const u16* Vh = VTb + (size_t)bh*HDIM*TT;
    const uint32_t* pmw = pmb + b*(TT/32);
    char* Pw = (char*)&Pl[w][0];

    // Q B-frags (pre-scaled by log2e/8): qf[qg][dc] = Q[qlo+qg*16+lr][dc*32+g*8..]
    bf16_8 qf[2][2];
    #pragma unroll
    for (int qg = 0; qg < 2; ++qg)
        #pragma unroll
        for (int dc = 0; dc < 2; ++dc)
            qf[qg][dc] = *(const bf16_8*)(Qh + (size_t)(qlo+qg*16+lr)*HDIM + dc*32 + g*8);

    f32x4 o[2][4];                    // O^T: o[qg][dt][r] = O[dt*16+4g+r][q=qlo+16qg+lr]
    #pragma unroll
    for (int qg = 0; qg < 2; ++qg)
        #pragma unroll
        for (int i = 0; i < 4; ++i) o[qg][i] = f32x4{0.f, 0.f, 0.f, 0.f};
    float m_run[2] = {-1e30f, -1e30f}, l_run[2] = {0.f, 0.f};

    const int nt    = 2*qt + 2;
    const int t_act = (qlo + 31) >> 6;               // wave's last needed tile

    auto STAGE = [&](int t, int buf) {
        int kv0 = t*64;
        #pragma unroll
        for (int r = 0; r < 2; ++r) {
            int o_  = r*256 + tid;        // 16B slot id = row*8 + chunk
            int row = o_ >> 3;
            int c   = (o_ & 7) ^ (row & 7);
            char* lk = (char*)&Ks[buf][0] + (size_t)(r*256 + w*64)*16;
            char* lv = (char*)&Vs[buf][0] + (size_t)(r*256 + w*64)*16;
            gload16(Kh + (size_t)(kv0+row)*HDIM + c*8, lk);
            gload16(Vh + (size_t)row*TT + kv0 + c*8, lv);
        }
    };

    STAGE(0, 0);
    asm volatile("s_waitcnt vmcnt(0)" ::: "memory");
    __builtin_amdgcn_s_barrier();

    for (int t = 0; t < nt; ++t) {
        const int cur = t & 1;
        if (t + 1 < nt) STAGE(t+1, cur^1);

        if (t <= t_act) {
            const int kv0 = t*64;
            const u16* Kc = &Ks[cur][0];
            const u16* Vc = &Vs[cur][0];

            // ---- QK^T swapped: s[qg][kvb] lane: q=qlo+16qg+lr, kv=kv0+16kvb+4g+reg
            f32x4 s[2][4];
            #pragma unroll
            for (int kvb = 0; kvb < 4; ++kvb) {
                int row = kvb*16 + lr;
                int sw  = row & 7;
                bf16_8 k0 = *(const bf16_8*)(Kc + row*64 + ((g    ) ^ sw)*8);
                bf16_8 k1 = *(const bf16_8*)(Kc + row*64 + ((4 + g) ^ sw)*8);
                #pragma unroll
                for (int qg = 0; qg < 2; ++qg) {
                    f32x4 z = f32x4{0.f, 0.f, 0.f, 0.f};
                    z = __builtin_amdgcn_mfma_f32_16x16x32_bf16(k0, qf[qg][0], z, 0, 0, 0);
                    z = __builtin_amdgcn_mfma_f32_16x16x32_bf16(k1, qf[qg][1], z, 0, 0, 0);
                    s[qg][kvb] = z;
                }
            }

            // ---- V^T A-frags (issued early; latency hides under softmax)
            bf16_8 vf[4][2];
            #pragma unroll
            for (int dt = 0; dt < 4; ++dt)
                #pragma unroll
                for (int hh = 0; hh < 2; ++hh)
                    vf[dt][hh] = *(const bf16_8*)(Vc + (dt*16+lr)*64 + ((hh*4+g) ^ (lr&7))*8);

            // ---- padding mask (scalar bits; skipped when all-clear)
            uint64_t m64 = (uint64_t)pmw[2*t] | ((uint64_t)pmw[2*t+1] << 32);
            if (m64) {
                #pragma unroll
                for (int kvb = 0; kvb < 4; ++kvb) {
                    uint32_t nib = (uint32_t)(m64 >> (kvb*16 + 4*g)) & 0xFu;
                    #pragma unroll
                    for (int r = 0; r < 4; ++r)
                        if ((nib >> r) & 1) { s[0][kvb][r] = -1e30f; s[1][kvb][r] = -1e30f; }
                }
            }
            // ---- causal mask (diagonal tile only)
            if (t == t_act) {
                #pragma unroll
                for (int qg = 0; qg < 2; ++qg) {
                    int q = qlo + qg*16 + lr;
                    #pragma unroll
                    for (int kvb = 0; kvb < 4; ++kvb) {
                        int kvb0 = kv0 + kvb*16 + 4*g;
                        #pragma unroll
                        for (int r = 0; r < 4; ++r)
                            if (kvb0 + r > q) s[qg][kvb][r] = -1e30f;
                    }
                }
            }

            // ---- online softmax (exp2 domain), per qg
            float mx[2], nm[2];
            #pragma unroll
            for (int qg = 0; qg < 2; ++qg) {
                float a = fmaxf(fmaxf(s[qg][0][0], s[qg][0][1]), fmaxf(s[qg][0][2], s[qg][0][3]));
                float c = fmaxf(fmaxf(s[qg][1][0], s[qg][1][1]), fmaxf(s[qg][1][2], s[qg][1][3]));
                float d = fmaxf(fmaxf(s[qg][2][0], s[qg][2][1]), fmaxf(s[qg][2][2], s[qg][2][3]));
                float e = fmaxf(fmaxf(s[qg][3][0], s[qg][3][1]), fmaxf(s[qg][3][2], s[qg][3][3]));
                float m = fmaxf(fmaxf(a, c), fmaxf(d, e));
                m = fmaxf(m, __shfl_xor(m, 16));
                m = fmaxf(m, __shfl_xor(m, 32));
                mx[qg] = m;
                nm[qg] = fmaxf(m_run[qg], m);
            }
            // rescale only when the max actually grew somewhere in the wave
            if (__any((mx[0] > m_run[0]) || (mx[1] > m_run[1]))) {
                float f0 = __builtin_amdgcn_exp2f(m_run[0] - nm[0]);
                float f1 = __builtin_amdgcn_exp2f(m_run[1] - nm[1]);
                #pragma unroll
                for (int dt = 0; dt < 4; ++dt)
                    #pragma unroll
                    for (int r = 0; r < 4; ++r) {
                        o[0][dt][r] *= f0;
                        o[1][dt][r] *= f1;
                    }
                l_run[0] *= f0; l_run[1] *= f1;
                m_run[0] = nm[0]; m_run[1] = nm[1];
            }

            #pragma unroll
            for (int qg = 0; qg < 2; ++qg) {
                #pragma unroll
                for (int kvb = 0; kvb < 4; ++kvb)
                    #pragma unroll
                    for (int r = 0; r < 4; ++r)
                        s[qg][kvb][r] = __builtin_amdgcn_exp2f(s[qg][kvb][r] - m_run[qg]);
                float p0 = (s[qg][0][0] + s[qg][0][1]) + (s[qg][0][2] + s[qg][0][3]);
                float p1 = (s[qg][1][0] + s[qg][1][1]) + (s[qg][1][2] + s[qg][1][3]);
                float p2 = (s[qg][2][0] + s[qg][2][1]) + (s[qg][2][2] + s[qg][2][3]);
                float p3 = (s[qg][3][0] + s[qg][3][1]) + (s[qg][3][2] + s[qg][3][3]);
                float ps = (p0 + p1) + (p2 + p3);
                ps += __shfl_xor(ps, 16);
                ps += __shfl_xor(ps, 32);
                l_run[qg] += ps;
            }

            // ---- P -> LDS (per-wave; compiler emits v_cvt_pk_bf16_f32 + ds_write_b64)
            #pragma unroll
            for (int qg = 0; qg < 2; ++qg)
                #pragma unroll
                for (int kvb = 0; kvb < 4; ++kvb) {
                    bf16_4 pk;
                    pk[0] = (__bf16)s[qg][kvb][0]; pk[1] = (__bf16)s[qg][kvb][1];
                    pk[2] = (__bf16)s[qg][kvb][2]; pk[3] = (__bf16)s[qg][kvb][3];
                    *(bf16_4*)(Pw + qg*2304 + lr*144 + kvb*32 + g*8) = pk;
                }
            asm volatile("s_waitcnt lgkmcnt(0)" ::: "memory");
            __builtin_amdgcn_sched_barrier(0);

            // ---- PV swapped: O^T += V^T(A) x P(B)
            #pragma unroll
            for (int qg = 0; qg < 2; ++qg)
                #pragma unroll
                for (int hh = 0; hh < 2; ++hh) {
                    bf16_8 pa = *(const bf16_8*)(Pw + qg*2304 + lr*144 + hh*64 + g*16);
                    #pragma unroll
                    for (int dt = 0; dt < 4; ++dt)
                        o[qg][dt] = __builtin_amdgcn_mfma_f32_16x16x32_bf16(
                            vf[dt][hh], pa, o[qg][dt], 0, 0, 0);
                }
        }

        asm volatile("s_waitcnt vmcnt(0)" ::: "memory");   // stage(t+1) landed
        __builtin_amdgcn_s_barrier();
    }

    // ---- epilogue: per-lane divide, LDS transpose, coalesced 128B row stores
    float linv[2];
    #pragma unroll
    for (int qg = 0; qg < 2; ++qg)
        linv[qg] = (l_run[qg] > 0.f) ? 1.f/l_run[qg] : 0.f;
    u16* ot = (u16*)Pw;                  // [qg][d 64][q 16] stride 17
    #pragma unroll
    for (int qg = 0; qg < 2; ++qg)
        #pragma unroll
        for (int dt = 0; dt < 4; ++dt)
            #pragma unroll
            for (int r = 0; r < 4; ++r)
                ot[qg*1088 + (dt*16 + 4*g + r)*17 + lr] = f2bf(o[qg][dt][r]*linv[qg]);
    asm volatile("s_waitcnt lgkmcnt(0)" ::: "memory");
    __builtin_amdgcn_sched_barrier(0);
    #pragma unroll
    for (int qg = 0; qg < 2; ++qg)
        #pragma unroll
        for (int qq = 0; qq < 16; ++qq) {
            int q = qlo + qg*16 + qq;
            AO[((size_t)(b*TT + q))*D_MODEL + h*HDIM + lane] = ot[qg*1088 + lane*17 + qq];
        }
}

// ---------------------------------------------------------------- launch
extern "C" void kernel_launch(void* const* d_in, const int* in_sizes, int n_in,
                              void* d_out, int out_size, void* d_ws, size_t ws_size,
                              hipStream_t stream)
{
    const float* x  = (const float*)d_in[0];
    const unsigned char* mask = (const unsigned char*)d_in[1];
    const float* Wq = (const float*)d_in[2];
    const float* Wk = (const float*)d_in[3];
    const float* Wv = (const float*)d_in[4];
    const float* Wo = (const float*)d_in[5];
    float* out = (float*)d_out;

    char* ws = (char*)d_ws;
    u16* xb  = (u16*)(ws + 0);          // 8 MB (reused as AO after QKV)
    u16* wqb = (u16*)(ws + 8388608);
    u16* wkb = (u16*)(ws + 10485760);
    u16* wvb = (u16*)(ws + 12582912);
    u16* wob = (u16*)(ws + 14680064);
    u16* Qb  = (u16*)(ws + 16777216);
    u16* Kb  = (u16*)(ws + 25165824);
    u16* VTb = (u16*)(ws + 33554432);
    uint32_t* pmb = (uint32_t*)(ws + 41943040);   // 512 B mask bits
    u16* AOb = xb;

    cvtk<<<dim3(1024, 6), 256, 0, stream>>>(x, Wq, Wk, Wv, Wo, mask,
                                            xb, wqb, wkb, wvb, wob, pmb);
    gemm_qkv<<<dim3(256, 3), 256, 0, stream>>>(xb, wqb, wkb, wvb, Qb, Kb, VTb);
    attn_fwd<<<dim3(TT/128, BB*NHEADS), 256, 0, stream>>>(Qb, Kb, VTb, pmb, AOb);
    gemm_out<<<dim3(256), 256, 0, stream>>>(AOb, wob, out);
}

// Round 5
// 143.979 us; speedup vs baseline: 2.1671x; 1.0224x over previous
//
#include <hip/hip_runtime.h>
#include <hip/hip_bf16.h>
#include <stdint.h>

#define D_MODEL 1024
#define NHEADS  16
#define HDIM    64
#define BB      2
#define TT      2048
#define MROWS   (BB*TT)      // 4096
#define GK      1024         // reduction dim for all projections

typedef __bf16 bf16_8 __attribute__((ext_vector_type(8)));
typedef __bf16 bf16_4 __attribute__((ext_vector_type(4)));
typedef float  f32x4  __attribute__((ext_vector_type(4)));
typedef unsigned short u16;

__device__ __forceinline__ u16 f2bf(float f) {
    union { float f; uint32_t u; } c; c.f = f;
    uint32_t u = c.u;
    uint32_t r = (u + 0x7FFFu + ((u >> 16) & 1u)) >> 16;
    return (u16)r;
}
__device__ __forceinline__ uint32_t pk2bf(float a, float b) {
    return (uint32_t)f2bf(a) | ((uint32_t)f2bf(b) << 16);
}

__device__ __forceinline__ void gload16(const void* g, void* l) {
    __builtin_amdgcn_global_load_lds(
        (const __attribute__((address_space(1))) unsigned int*)g,
        (__attribute__((address_space(3))) unsigned int*)l,
        16, 0, 0);
}

// ---------------------------------------------------------------- convert
__global__ __launch_bounds__(256) void cvtk(
    const float* __restrict__ x,  const float* __restrict__ wq,
    const float* __restrict__ wk, const float* __restrict__ wv,
    const float* __restrict__ wo, const unsigned char* __restrict__ mk,
    u16* __restrict__ xb,  u16* __restrict__ wqb, u16* __restrict__ wkb,
    u16* __restrict__ wvb, u16* __restrict__ wob, uint32_t* __restrict__ pmb)
{
    int z = blockIdx.y;
    if (z == 5) {   // pack padding mask bits: pmb[b*64 + i], bit j = mask[b][32i+j]
        int gi = blockIdx.x*256 + threadIdx.x;
        if (gi < BB*TT/32) {
            uint32_t wv = 0;
            #pragma unroll
            for (int j = 0; j < 32; ++j)
                wv |= (mk[gi*32 + j] ? 1u : 0u) << j;
            pmb[gi] = wv;
        }
        return;
    }
    const float* in; u16* out; int n4;
    switch (z) {
        case 0: in = x;  out = xb;  n4 = MROWS*D_MODEL/4; break;
        case 1: in = wq; out = wqb; n4 = D_MODEL*D_MODEL/4; break;
        case 2: in = wk; out = wkb; n4 = D_MODEL*D_MODEL/4; break;
        case 3: in = wv; out = wvb; n4 = D_MODEL*D_MODEL/4; break;
        default: in = wo; out = wob; n4 = D_MODEL*D_MODEL/4; break;
    }
    for (int i = blockIdx.x*256 + threadIdx.x; i < n4; i += 1024*256) {
        float4 v = ((const float4*)in)[i];
        uint2 pk;
        pk.x = pk2bf(v.x, v.y);
        pk.y = pk2bf(v.z, v.w);
        ((uint2*)out)[i] = pk;
    }
}

// ---------------------------------------------------------------- GEMM body
// C(128x128) tile of A(4096x1024) * B(1024x1024)^T, both bf16 row-major.
// MODE 0: scatter bf16 into (B,H,T,D)   [Q (scaled), K]
// MODE 1: swapped-operand MFMA; store bf16 into (B,H,D,T) coalesced  [V^T]
// MODE 2: f32 row-major (4096x1024)     [final out]
// NB: LDS buffers. NB=2: raw-barrier pipelined (for 1-block/CU launches);
//     NB=1: classic 2x syncthreads (keeps 3+ blocks/CU for gemm_qkv).
template<int MODE, int NB>
__device__ __forceinline__ void gemm_body(
    const u16* __restrict__ A, const u16* __restrict__ Bm,
    void* __restrict__ dst, float oscale)
{
    __shared__ u16 As[NB][128*64];
    __shared__ u16 Bs[NB][128*64];
    const int tid  = threadIdx.x;
    const int lane = tid & 63, w = tid >> 6;
    const int wr = w >> 1, wc = w & 1;
    const int g = lane >> 4, lr = lane & 15;
    const int bn = blockIdx.x & 7, bm = blockIdx.x >> 3;
    const int m0 = bm * 128, n0 = bn * 128;

    f32x4 acc[4][4];
    #pragma unroll
    for (int i = 0; i < 4; ++i)
        #pragma unroll
        for (int j = 0; j < 4; ++j)
            acc[i][j] = f32x4{0.f, 0.f, 0.f, 0.f};

    auto STG = [&](int kt, int buf) {
        int k0 = kt*64;
        #pragma unroll
        for (int r = 0; r < 4; ++r) {
            int o   = r*256 + tid;
            int row = o >> 3;
            int lc  = (o & 7) ^ (row & 7);
            gload16(A  + (size_t)(m0+row)*GK + k0 + lc*8,
                    (char*)&As[buf][0] + (size_t)(r*256 + w*64)*16);
            gload16(Bm + (size_t)(n0+row)*GK + k0 + lc*8,
                    (char*)&Bs[buf][0] + (size_t)(r*256 + w*64)*16);
        }
    };
    auto CMP = [&](const u16* Asc, const u16* Bsc) {
        #pragma unroll
        for (int ks = 0; ks < 2; ++ks) {
            bf16_8 af[4], bfr[4];
            #pragma unroll
            for (int mt = 0; mt < 4; ++mt) {
                int row = wr*64 + mt*16 + lr;
                int ch  = (ks*4 + g) ^ (row & 7);
                af[mt] = *(const bf16_8*)((const char*)Asc + row*128 + ch*16);
            }
            #pragma unroll
            for (int nt = 0; nt < 4; ++nt) {
                int row = wc*64 + nt*16 + lr;
                int ch  = (ks*4 + g) ^ (row & 7);
                bfr[nt] = *(const bf16_8*)((const char*)Bsc + row*128 + ch*16);
            }
            #pragma unroll
            for (int mt = 0; mt < 4; ++mt)
                #pragma unroll
                for (int nt = 0; nt < 4; ++nt) {
                    if (MODE == 1)
                        acc[mt][nt] = __builtin_amdgcn_mfma_f32_16x16x32_bf16(
                            bfr[nt], af[mt], acc[mt][nt], 0, 0, 0);
                    else
                        acc[mt][nt] = __builtin_amdgcn_mfma_f32_16x16x32_bf16(
                            af[mt], bfr[nt], acc[mt][nt], 0, 0, 0);
                }
        }
    };

    if (NB == 2) {
        // pipelined: wait(stage kt) -> barrier -> issue stage kt+1 -> compute kt
        STG(0, 0);
        for (int kt = 0; kt < 16; ++kt) {
            asm volatile("s_waitcnt vmcnt(0)" ::: "memory");
            __builtin_amdgcn_s_barrier();
            if (kt + 1 < 16) STG(kt+1, (kt+1) & 1);
            CMP(&As[kt & 1][0], &Bs[kt & 1][0]);
        }
    } else {
        for (int kt = 0; kt < 16; ++kt) {
            STG(kt, 0);
            __syncthreads();
            CMP(&As[0][0], &Bs[0][0]);
            __syncthreads();
        }
    }

    #pragma unroll
    for (int mt = 0; mt < 4; ++mt) {
        #pragma unroll
        for (int nt = 0; nt < 4; ++nt) {
            #pragma unroll
            for (int r = 0; r < 4; ++r) {
                float v = acc[mt][nt][r];
                if (MODE == 2) {
                    int row = m0 + wr*64 + mt*16 + g*4 + r;
                    int col = n0 + wc*64 + nt*16 + lr;
                    ((float*)dst)[(size_t)row*D_MODEL + col] = v;
                } else if (MODE == 0) {
                    int row = m0 + wr*64 + mt*16 + g*4 + r;   // m: (b,t)
                    int col = n0 + wc*64 + nt*16 + lr;        // n: (h,d)
                    int b = row >> 11, t = row & (TT-1);
                    int h = col >> 6,  d = col & 63;
                    ((u16*)dst)[(((size_t)(b*NHEADS + h)*TT + t)*HDIM + d)] = f2bf(v*oscale);
                } else {  // MODE 1: acc row = n-side (h,d), col = m-side (b,t)
                    int nrow = n0 + wc*64 + nt*16 + g*4 + r;  // n: (h,d)
                    int mcol = m0 + wr*64 + mt*16 + lr;       // m: (b,t)
                    int h = nrow >> 6,  d = nrow & 63;
                    int b = mcol >> 11, t = mcol & (TT-1);
                    ((u16*)dst)[(((size_t)(b*NHEADS + h)*HDIM + d)*TT + t)] = f2bf(v);
                }
            }
        }
    }
}

__global__ __launch_bounds__(256) void gemm_qkv(
    const u16* __restrict__ xb,
    const u16* __restrict__ wqb, const u16* __restrict__ wkb, const u16* __restrict__ wvb,
    u16* __restrict__ Qb, u16* __restrict__ Kb, u16* __restrict__ VTb)
{
    int z = blockIdx.y;
    if (z == 0)      gemm_body<0,1>(xb, wqb, Qb, 0.18033688f);  // (1/8)*log2(e)
    else if (z == 1) gemm_body<0,1>(xb, wkb, Kb, 1.0f);
    else             gemm_body<1,1>(xb, wvb, VTb, 1.0f);
}

__global__ __launch_bounds__(256) void gemm_out(
    const u16* __restrict__ AOb, const u16* __restrict__ wob, float* __restrict__ out)
{
    gemm_body<2,2>(AOb, wob, out, 1.0f);
}

// ---------------------------------------------------------------- attention
// grid (T/128, B*H); 4 waves x 32 q-rows; KVBLK=64, 3 LDS buffers (depth-2
// prefetch): wait vmcnt(4) -> barrier -> STAGE(t+2) -> compute(t). Mask bits
// in LDS (lgkm path) so nothing but stages rides the vmcnt counter.
__global__ __launch_bounds__(256, 2) void attn_fwd(
    const u16* __restrict__ Qb, const u16* __restrict__ Kb,
    const u16* __restrict__ VTb, const uint32_t* __restrict__ pmb,
    u16* __restrict__ AO)
{
    __shared__ u16 Ks[3][64*64];      // 24 KB
    __shared__ u16 Vs[3][64*64];      // 24 KB
    __shared__ u16 Pl[4][2304];       // 18 KB per-wave P / epilogue transpose
    __shared__ uint32_t Ml[64];       // mask bits for this batch (256 B)

    const int tid = threadIdx.x, lane = tid & 63, w = tid >> 6;
    const int g = lane >> 4, lr = lane & 15;
    const int bh = blockIdx.y, b = bh >> 4, h = bh & 15;
    const int qt = gridDim.x - 1 - blockIdx.x;       // heavy tiles first
    const int qlo = qt*128 + w*32;                   // wave's 32 q-rows

    const u16* Qh = Qb  + (size_t)bh*TT*HDIM;
    const u16* Kh = Kb  + (size_t)bh*TT*HDIM;
    const u16* Vh = VTb + (size_t)bh*HDIM*TT;
    char* Pw = (char*)&Pl[w][0];

    if (tid < 64) Ml[tid] = pmb[b*(TT/32) + tid];

    // Q B-frags (pre-scaled by log2e/8): qf[qg][dc] = Q[qlo+qg*16+lr][dc*32+g*8..]
    bf16_8 qf[2][2];
    #pragma unroll
    for (int qg = 0; qg < 2; ++qg)
        #pragma unroll
        for (int dc = 0; dc < 2; ++dc)
            qf[qg][dc] = *(const bf16_8*)(Qh + (size_t)(qlo+qg*16+lr)*HDIM + dc*32 + g*8);

    f32x4 o[2][4];                    // O^T: o[qg][dt][r] = O[dt*16+4g+r][q=qlo+16qg+lr]
    #pragma unroll
    for (int qg = 0; qg < 2; ++qg)
        #pragma unroll
        for (int i = 0; i < 4; ++i) o[qg][i] = f32x4{0.f, 0.f, 0.f, 0.f};
    float m_run[2] = {-1e30f, -1e30f}, l_run[2] = {0.f, 0.f};

    const int nt    = 2*qt + 2;
    const int t_act = (qlo + 31) >> 6;               // wave's last needed tile

    auto STAGE = [&](int t, int buf) {
        int kv0 = t*64;
        #pragma unroll
        for (int r = 0; r < 2; ++r) {
            int o_  = r*256 + tid;        // 16B slot id = row*8 + chunk
            int row = o_ >> 3;
            int c   = (o_ & 7) ^ (row & 7);
            char* lk = (char*)&Ks[buf][0] + (size_t)(r*256 + w*64)*16;
            char* lv = (char*)&Vs[buf][0] + (size_t)(r*256 + w*64)*16;
            gload16(Kh + (size_t)(kv0+row)*HDIM + c*8, lk);
            gload16(Vh + (size_t)row*TT + kv0 + c*8, lv);
        }
    };

    STAGE(0, 0);          // nt >= 2 always
    STAGE(1, 1);

    int cur = 0;
    for (int t = 0; t < nt; ++t) {
        // wait for stage(t): stage(t+1) [4 loads] may stay in flight
        if (t + 1 < nt) asm volatile("s_waitcnt vmcnt(4) lgkmcnt(0)" ::: "memory");
        else            asm volatile("s_waitcnt vmcnt(0) lgkmcnt(0)" ::: "memory");
        __builtin_amdgcn_s_barrier();
        if (t + 2 < nt) { int nb = cur + 2; if (nb >= 3) nb -= 3; STAGE(t+2, nb); }

        if (t <= t_act) {
            const int kv0 = t*64;
            const u16* Kc = &Ks[cur][0];
            const u16* Vc = &Vs[cur][0];

            // ---- QK^T swapped: s[qg][kvb] lane: q=qlo+16qg+lr, kv=kv0+16kvb+4g+reg
            f32x4 s[2][4];
            __builtin_amdgcn_s_setprio(1);
            #pragma unroll
            for (int kvb = 0; kvb < 4; ++kvb) {
                int row = kvb*16 + lr;
                int sw  = row & 7;
                bf16_8 k0 = *(const bf16_8*)(Kc + row*64 + ((g    ) ^ sw)*8);
                bf16_8 k1 = *(const bf16_8*)(Kc + row*64 + ((4 + g) ^ sw)*8);
                #pragma unroll
                for (int qg = 0; qg < 2; ++qg) {
                    f32x4 z = f32x4{0.f, 0.f, 0.f, 0.f};
                    z = __builtin_amdgcn_mfma_f32_16x16x32_bf16(k0, qf[qg][0], z, 0, 0, 0);
                    z = __builtin_amdgcn_mfma_f32_16x16x32_bf16(k1, qf[qg][1], z, 0, 0, 0);
                    s[qg][kvb] = z;
                }
            }
            __builtin_amdgcn_s_setprio(0);

            // ---- V^T A-frags (LDS; latency hides under softmax)
            bf16_8 vf[4][2];
            #pragma unroll
            for (int dt = 0; dt < 4; ++dt)
                #pragma unroll
                for (int hh = 0; hh < 2; ++hh)
                    vf[dt][hh] = *(const bf16_8*)(Vc + (dt*16+lr)*64 + ((hh*4+g) ^ (lr&7))*8);

            // ---- padding mask from LDS bits (skipped when all-clear)
            uint64_t m64 = (uint64_t)Ml[2*t] | ((uint64_t)Ml[2*t+1] << 32);
            if (m64) {
                #pragma unroll
                for (int kvb = 0; kvb < 4; ++kvb) {
                    uint32_t nib = (uint32_t)(m64 >> (kvb*16 + 4*g)) & 0xFu;
                    #pragma unroll
                    for (int r = 0; r < 4; ++r)
                        if ((nib >> r) & 1) { s[0][kvb][r] = -1e30f; s[1][kvb][r] = -1e30f; }
                }
            }
            // ---- causal mask (diagonal tile only)
            if (t == t_act) {
                #pragma unroll
                for (int qg = 0; qg < 2; ++qg) {
                    int q = qlo + qg*16 + lr;
                    #pragma unroll
                    for (int kvb = 0; kvb < 4; ++kvb) {
                        int kvb0 = kv0 + kvb*16 + 4*g;
                        #pragma unroll
                        for (int r = 0; r < 4; ++r)
                            if (kvb0 + r > q) s[qg][kvb][r] = -1e30f;
                    }
                }
            }

            // ---- online softmax (exp2 domain) with defer-max THR=8 (T13)
            float mx[2];
            #pragma unroll
            for (int qg = 0; qg < 2; ++qg) {
                float a = fmaxf(fmaxf(s[qg][0][0], s[qg][0][1]), fmaxf(s[qg][0][2], s[qg][0][3]));
                float c = fmaxf(fmaxf(s[qg][1][0], s[qg][1][1]), fmaxf(s[qg][1][2], s[qg][1][3]));
                float d = fmaxf(fmaxf(s[qg][2][0], s[qg][2][1]), fmaxf(s[qg][2][2], s[qg][2][3]));
                float e = fmaxf(fmaxf(s[qg][3][0], s[qg][3][1]), fmaxf(s[qg][3][2], s[qg][3][3]));
                float m = fmaxf(fmaxf(a, c), fmaxf(d, e));
                m = fmaxf(m, __shfl_xor(m, 16));
                m = fmaxf(m, __shfl_xor(m, 32));
                mx[qg] = m;
            }
            bool need = (mx[0] > m_run[0] + 8.f) || (mx[1] > m_run[1] + 8.f);
            if (__any(need)) {
                float nm0 = fmaxf(m_run[0], mx[0]);
                float nm1 = fmaxf(m_run[1], mx[1]);
                float f0 = __builtin_amdgcn_exp2f(m_run[0] - nm0);
                float f1 = __builtin_amdgcn_exp2f(m_run[1] - nm1);
                #pragma unroll
                for (int dt = 0; dt < 4; ++dt)
                    #pragma unroll
                    for (int r = 0; r < 4; ++r) {
                        o[0][dt][r] *= f0;
                        o[1][dt][r] *= f1;
                    }
                l_run[0] *= f0; l_run[1] *= f1;
                m_run[0] = nm0; m_run[1] = nm1;
            }

            #pragma unroll
            for (int qg = 0; qg < 2; ++qg) {
                #pragma unroll
                for (int kvb = 0; kvb < 4; ++kvb)
                    #pragma unroll
                    for (int r = 0; r < 4; ++r)
                        s[qg][kvb][r] = __builtin_amdgcn_exp2f(s[qg][kvb][r] - m_run[qg]);
                float p0 = (s[qg][0][0] + s[qg][0][1]) + (s[qg][0][2] + s[qg][0][3]);
                float p1 = (s[qg][1][0] + s[qg][1][1]) + (s[qg][1][2] + s[qg][1][3]);
                float p2 = (s[qg][2][0] + s[qg][2][1]) + (s[qg][2][2] + s[qg][2][3]);
                float p3 = (s[qg][3][0] + s[qg][3][1]) + (s[qg][3][2] + s[qg][3][3]);
                float ps = (p0 + p1) + (p2 + p3);
                ps += __shfl_xor(ps, 16);
                ps += __shfl_xor(ps, 32);
                l_run[qg] += ps;
            }

            // ---- P -> LDS (per-wave; v_cvt_pk_bf16_f32 + ds_write_b64)
            #pragma unroll
            for (int qg = 0; qg < 2; ++qg)
                #pragma unroll
                for (int kvb = 0; kvb < 4; ++kvb) {
                    bf16_4 pk;
                    pk[0] = (__bf16)s[qg][kvb][0]; pk[1] = (__bf16)s[qg][kvb][1];
                    pk[2] = (__bf16)s[qg][kvb][2]; pk[3] = (__bf16)s[qg][kvb][3];
                    *(bf16_4*)(Pw + qg*2304 + lr*144 + kvb*32 + g*8) = pk;
                }
            asm volatile("s_waitcnt lgkmcnt(0)" ::: "memory");
            __builtin_amdgcn_sched_barrier(0);

            // ---- PV swapped: O^T += V^T(A) x P(B)
            __builtin_amdgcn_s_setprio(1);
            #pragma unroll
            for (int qg = 0; qg < 2; ++qg)
                #pragma unroll
                for (int hh = 0; hh < 2; ++hh) {
                    bf16_8 pa = *(const bf16_8*)(Pw + qg*2304 + lr*144 + hh*64 + g*16);
                    #pragma unroll
                    for (int dt = 0; dt < 4; ++dt)
                        o[qg][dt] = __builtin_amdgcn_mfma_f32_16x16x32_bf16(
                            vf[dt][hh], pa, o[qg][dt], 0, 0, 0);
                }
            __builtin_amdgcn_s_setprio(0);
        }

        ++cur; if (cur == 3) cur = 0;
    }

    // ---- epilogue: per-lane divide, LDS transpose, coalesced 128B row stores
    float linv[2];
    #pragma unroll
    for (int qg = 0; qg < 2; ++qg)
        linv[qg] = (l_run[qg] > 0.f) ? 1.f/l_run[qg] : 0.f;
    u16* ot = (u16*)Pw;                  // [qg][d 64][q 16] stride 17
    #pragma unroll
    for (int qg = 0; qg < 2; ++qg)
        #pragma unroll
        for (int dt = 0; dt < 4; ++dt)
            #pragma unroll
            for (int r = 0; r < 4; ++r)
                ot[qg*1088 + (dt*16 + 4*g + r)*17 + lr] = f2bf(o[qg][dt][r]*linv[qg]);
    asm volatile("s_waitcnt lgkmcnt(0)" ::: "memory");
    __builtin_amdgcn_sched_barrier(0);
    #pragma unroll
    for (int qg = 0; qg < 2; ++qg)
        #pragma unroll
        for (int qq = 0; qq < 16; ++qq) {
            int q = qlo + qg*16 + qq;
            AO[((size_t)(b*TT + q))*D_MODEL + h*HDIM + lane] = ot[qg*1088 + lane*17 + qq];
        }
}

// ---------------------------------------------------------------- launch
extern "C" void kernel_launch(void* const* d_in, const int* in_sizes, int n_in,
                              void* d_out, int out_size, void* d_ws, size_t ws_size,
                              hipStream_t stream)
{
    const float* x  = (const float*)d_in[0];
    const unsigned char* mask = (const unsigned char*)d_in[1];
    const float* Wq = (const float*)d_in[2];
    const float* Wk = (const float*)d_in[3];
    const float* Wv = (const float*)d_in[4];
    const float* Wo = (const float*)d_in[5];
    float* out = (float*)d_out;

    char* ws = (char*)d_ws;
    u16* xb  = (u16*)(ws + 0);          // 8 MB (reused as AO after QKV)
    u16* wqb = (u16*)(ws + 8388608);
    u16* wkb = (u16*)(ws + 10485760);
    u16* wvb = (u16*)(ws + 12582912);
    u16* wob = (u16*)(ws + 14680064);
    u16* Qb  = (u16*)(ws + 16777216);
    u16* Kb  = (u16*)(ws + 25165824);
    u16* VTb = (u16*)(ws + 33554432);
    uint32_t* pmb = (uint32_t*)(ws + 41943040);   // 512 B mask bits
    u16* AOb = xb;

    cvtk<<<dim3(1024, 6), 256, 0, stream>>>(x, Wq, Wk, Wv, Wo, mask,
                                            xb, wqb, wkb, wvb, wob, pmb);
    gemm_qkv<<<dim3(256, 3), 256, 0, stream>>>(xb, wqb, wkb, wvb, Qb, Kb, VTb);
    attn_fwd<<<dim3(TT/128, BB*NHEADS), 256, 0, stream>>>(Qb, Kb, VTb, pmb, AOb);
    gemm_out<<<dim3(256), 256, 0, stream>>>(AOb, wob, out);
}